// Round 4
// baseline (285.388 us; speedup 1.0000x reference)
//
#include <hip/hip_runtime.h>

// LowRankRotatedSpaceIntervention — fused single-pass kernel, v4.
// out[b,:] = base[b,:] + (mask_b . ((source[b,:]-base[b,:]) @ W)) @ W^T
// B=16384, D=4096, R=64, 8 partitions of 8, 4 selected per row.
//
// v4 vs v3: phase-1 A-fragments are built ENTIRELY in registers — each lane
// loads base/src directly in MFMA-A arrangement (row=l4, k=s*32+g*8..+8),
// diffs and packs to bf16 in-register. No stage LDS, no ds round-trip, no
// barrier in the K-loop; the loop is pure loads+VALU+MFMA and fully unrolled
// so the compiler can pipeline loads ~3 iterations deep (R3 showed VGPR=48
// strangled MLP: BW plateaued at 2.3 TB/s regardless of occupancy).
// Phase 2: fully unrolled, alternating cbuf halves to break cross-iteration
// LDS dependencies. LDS 39KB -> 4 blocks/CU.

#define D_DIM 4096
#define R_DIM 64
#define BM    16
#define KC    64
#define KW    1024

typedef short bf16vec8 __attribute__((ext_vector_type(8)));
typedef float f32x4v  __attribute__((ext_vector_type(4)));

// LDS layout: 4 waves * 2 * [16][72] f32 scratch (partials / double cbuf), rm
#define WAVE_SCR_F  2304                  // floats per wave (2 x 1152)
#define OFF_RM      36864                 // bytes; [16][64] bf16 = 2048
#define SMEM_BYTES  38912                 // <= 40960 -> 4 blocks/CU

__device__ __forceinline__ unsigned int f2bf_u(float f) {
  unsigned int u = __builtin_bit_cast(unsigned int, f);
  return (u + 0x7fffu + ((u >> 16) & 1u)) >> 16;   // RNE
}
__device__ __forceinline__ unsigned int pack2bf(float a, float b) {
  return f2bf_u(a) | (f2bf_u(b) << 16);
}

__global__ __launch_bounds__(256)
void lrri_prep(const float* __restrict__ W, unsigned short* __restrict__ Wt,
               unsigned short* __restrict__ Wb) {
  const int idx = blockIdx.x * blockDim.x + threadIdx.x;   // 0..65535
  const int k = idx >> 4;
  const int j = (idx & 15) * 4;
  float4 w = *(const float4*)(W + (size_t)k * R_DIM + j);
  ushort4 p;
  p.x = (unsigned short)f2bf_u(w.x);
  p.y = (unsigned short)f2bf_u(w.y);
  p.z = (unsigned short)f2bf_u(w.z);
  p.w = (unsigned short)f2bf_u(w.w);
  *(ushort4*)(Wb + (size_t)k * R_DIM + j) = p;     // [4096][64] bf16
  Wt[(size_t)(j + 0) * D_DIM + k] = p.x;           // [64][4096] bf16
  Wt[(size_t)(j + 1) * D_DIM + k] = p.y;
  Wt[(size_t)(j + 2) * D_DIM + k] = p.z;
  Wt[(size_t)(j + 3) * D_DIM + k] = p.w;
}

template<bool USE_WS>
__global__ __launch_bounds__(256, 4)
void lrri_fused(const float* __restrict__ base, const float* __restrict__ srcp,
                const float* __restrict__ W, const int* __restrict__ subs,
                const unsigned short* __restrict__ Wt_bf,   // [64][4096]
                const unsigned short* __restrict__ Wb_bf,   // [4096][64]
                float* __restrict__ out)
{
  __shared__ __align__(16) unsigned char smem[SMEM_BYTES];
  const int tid  = threadIdx.x;
  const int wave = tid >> 6;
  const int lane = tid & 63;
  const int l4   = lane & 15;
  const int g    = lane >> 4;
  const long rowbase = (long)blockIdx.x * BM;

  // ---------------- Phase 1: r = (src-base) @ W, all in registers ---------
  f32x4v acc[4];
  #pragma unroll
  for (int t = 0; t < 4; ++t) acc[t] = (f32x4v){0.f, 0.f, 0.f, 0.f};

  const int  kw0  = wave * KW;
  const long arow = (rowbase + l4) * D_DIM;     // this lane's A row

  #pragma unroll
  for (int c = 0; c < KW / KC; ++c) {
    const int kbase = kw0 + c * KC;
    // loads in A-fragment arrangement: q = s*2+half, 8 consecutive k per s
    float4 vb[4], vs[4];
    #pragma unroll
    for (int q = 0; q < 4; ++q) {
      const long off = arow + kbase + (q >> 1) * 32 + g * 8 + (q & 1) * 4;
      vb[q] = *(const float4*)(base + off);
      vs[q] = *(const float4*)(srcp + off);
    }
    uint4 af[2];
    #pragma unroll
    for (int s = 0; s < 2; ++s) {
      float d0 = vs[s*2].x - vb[s*2].x, d1 = vs[s*2].y - vb[s*2].y;
      float d2 = vs[s*2].z - vb[s*2].z, d3 = vs[s*2].w - vb[s*2].w;
      float d4 = vs[s*2+1].x - vb[s*2+1].x, d5 = vs[s*2+1].y - vb[s*2+1].y;
      float d6 = vs[s*2+1].z - vb[s*2+1].z, d7 = vs[s*2+1].w - vb[s*2+1].w;
      af[s].x = pack2bf(d0, d1);
      af[s].y = pack2bf(d2, d3);
      af[s].z = pack2bf(d4, d5);
      af[s].w = pack2bf(d6, d7);
    }
    #pragma unroll
    for (int t = 0; t < 4; ++t) {
      #pragma unroll
      for (int s = 0; s < 2; ++s) {
        uint4 bfrag;
        if (USE_WS) {
          bfrag = *(const uint4*)(Wt_bf + (size_t)(t * 16 + l4) * D_DIM +
                                  kbase + s * 32 + g * 8);
        } else {
          unsigned int p[4];
          #pragma unroll
          for (int e2 = 0; e2 < 4; ++e2) {
            float wa = W[(size_t)(kbase + s * 32 + g * 8 + e2 * 2    ) * R_DIM + t * 16 + l4];
            float wb = W[(size_t)(kbase + s * 32 + g * 8 + e2 * 2 + 1) * R_DIM + t * 16 + l4];
            p[e2] = pack2bf(wa, wb);
          }
          bfrag.x = p[0]; bfrag.y = p[1]; bfrag.z = p[2]; bfrag.w = p[3];
        }
        acc[t] = __builtin_amdgcn_mfma_f32_16x16x32_bf16(
            __builtin_bit_cast(bf16vec8, af[s]),
            __builtin_bit_cast(bf16vec8, bfrag), acc[t], 0, 0, 0);
      }
    }
  }
  // write per-wave partials: C/D layout row=(g*4+i), col=l4 within j-tile t
  {
    float* part = (float*)smem + wave * WAVE_SCR_F;
    #pragma unroll
    for (int t = 0; t < 4; ++t)
      #pragma unroll
      for (int i = 0; i < 4; ++i)
        part[(g * 4 + i) * 72 + t * 16 + l4] = acc[t][i];
  }
  __syncthreads();

  // ---------------- Reduce partials + per-row partition mask --------------
  {
    const int row = tid >> 4, jg = tid & 15;
    const float* p0 = (const float*)smem;
    int4 sb = *(const int4*)(subs + (rowbase + row) * 4);
    unsigned mbits = (1u << sb.x) | (1u << sb.y) | (1u << sb.z) | (1u << sb.w);
    unsigned short vals[4];
    #pragma unroll
    for (int jj = 0; jj < 4; ++jj) {
      const int j = jg * 4 + jj;
      float sum = p0[row * 72 + j] + p0[WAVE_SCR_F + row * 72 + j] +
                  p0[2 * WAVE_SCR_F + row * 72 + j] +
                  p0[3 * WAVE_SCR_F + row * 72 + j];
      vals[jj] = ((mbits >> (j >> 3)) & 1u) ? (unsigned short)f2bf_u(sum)
                                            : (unsigned short)0;
    }
    unsigned short* rm = (unsigned short*)(smem + OFF_RM);
    uint2 pk;
    pk.x = (unsigned)vals[0] | ((unsigned)vals[1] << 16);
    pk.y = (unsigned)vals[2] | ((unsigned)vals[3] << 16);
    *(uint2*)(rm + row * 64 + jg * 4) = pk;
  }
  __syncthreads();

  // ---------------- Phase 2: out = base(global) + rm @ W^T ----------------
  uint4 a2[2];
  {
    const unsigned char* rm = smem + OFF_RM;
    #pragma unroll
    for (int s = 0; s < 2; ++s)
      a2[s] = *(const uint4*)(rm + l4 * 128 + s * 64 + g * 16);
  }
  float* cb = (float*)smem + wave * WAVE_SCR_F;
  #pragma unroll
  for (int grp = 0; grp < 16; ++grp) {
    const int cbase = wave * 1024 + grp * 64;
    // base re-reads (L2/L3-mostly) issued early; independent of MFMAs
    float4 bb[4];
    #pragma unroll
    for (int s2 = 0; s2 < 4; ++s2) {
      const int r = g + s2 * 4;
      bb[s2] = *(const float4*)(base + (rowbase + r) * D_DIM + cbase + l4 * 4);
    }
    float* cbuf = cb + (grp & 1) * 1152;      // alternate halves across grps
    #pragma unroll
    for (int t = 0; t < 4; ++t) {
      f32x4v a = (f32x4v){0.f, 0.f, 0.f, 0.f};
      #pragma unroll
      for (int s = 0; s < 2; ++s) {
        uint4 bfrag;  // B[kk=j][n=col] = W[col][j]; per-lane 8 consecutive j
        if (USE_WS) {
          bfrag = *(const uint4*)(Wb_bf + (size_t)(cbase + t * 16 + l4) * R_DIM +
                                  s * 32 + g * 8);
        } else {
          const float* wp = W + (size_t)(cbase + t * 16 + l4) * R_DIM + s * 32 + g * 8;
          float4 wa = *(const float4*)(wp);
          float4 wb = *(const float4*)(wp + 4);
          bfrag.x = pack2bf(wa.x, wa.y); bfrag.y = pack2bf(wa.z, wa.w);
          bfrag.z = pack2bf(wb.x, wb.y); bfrag.w = pack2bf(wb.z, wb.w);
        }
        a = __builtin_amdgcn_mfma_f32_16x16x32_bf16(
            __builtin_bit_cast(bf16vec8, a2[s]),
            __builtin_bit_cast(bf16vec8, bfrag), a, 0, 0, 0);
      }
      #pragma unroll
      for (int i = 0; i < 4; ++i)
        cbuf[(g * 4 + i) * 72 + t * 16 + l4] = a[i];
    }
    // transpose via wave-local LDS -> coalesced float4 stores
    #pragma unroll
    for (int s2 = 0; s2 < 4; ++s2) {
      const int r = g + s2 * 4;
      f32x4v cv = *(const f32x4v*)(cbuf + r * 72 + l4 * 4);
      float4 o;
      o.x = cv[0] + bb[s2].x;
      o.y = cv[1] + bb[s2].y;
      o.z = cv[2] + bb[s2].z;
      o.w = cv[3] + bb[s2].w;
      *(float4*)(out + (rowbase + r) * D_DIM + cbase + l4 * 4) = o;
    }
  }
}

extern "C" void kernel_launch(void* const* d_in, const int* in_sizes, int n_in,
                              void* d_out, int out_size, void* d_ws, size_t ws_size,
                              hipStream_t stream) {
  const float* base = (const float*)d_in[0];
  const float* srcp = (const float*)d_in[1];
  const float* W    = (const float*)d_in[2];
  const int*   subs = (const int*)d_in[3];
  float* out = (float*)d_out;

  const int nblocks = 16384 / BM;   // 1024
  const size_t wbytes = (size_t)2 * R_DIM * D_DIM * sizeof(unsigned short); // 1 MB
  if (d_ws && ws_size >= wbytes) {
    unsigned short* Wt = (unsigned short*)d_ws;          // [64][4096] bf16
    unsigned short* Wb = Wt + (size_t)R_DIM * D_DIM;     // [4096][64] bf16
    lrri_prep<<<256, 256, 0, stream>>>(W, Wt, Wb);
    lrri_fused<true><<<nblocks, 256, 0, stream>>>(base, srcp, W, subs, Wt, Wb, out);
  } else {
    lrri_fused<false><<<nblocks, 256, 0, stream>>>(base, srcp, W, subs, nullptr, nullptr, out);
  }
}

// Round 5
// 252.310 us; speedup vs baseline: 1.1311x; 1.1311x over previous
//
#include <hip/hip_runtime.h>

// LowRankRotatedSpaceIntervention — fused single-pass kernel, v5.
// out[b,:] = base[b,:] + (mask_b . ((source[b,:]-base[b,:]) @ W)) @ W^T
// B=16384, D=4096, R=64, 8 partitions of 8, 4 selected per row.
//
// v5: phase-1 staging via __builtin_amdgcn_global_load_lds (width=16) —
// async direct-to-LDS, no result VGPRs, so 8x1KB loads per iter are issued
// back-to-back and stay in flight (R1-R4 all pinned at 2.3 TB/s because
// register staging kept VGPR_Count at 48-64 => ~1 load in flight per wave).
// Wave-private double-buffered staging => NO barrier in the K-loop.
// global_load_lds writes LDS linearly, so the per-lane GLOBAL source address
// is pre-swizzled (XOR bits 4-6 with row&7); the swizzled ds_read_b128 then
// cancels the XOR => canonical k-order, conflict-free (2-way) A-frag reads.
// BM=32, 512 blocks, 4 waves = (row-half, K-half), LDS 70 KB -> 2 blocks/CU.

#define D_DIM 4096
#define R_DIM 64
#define BM    32
#define WAVESTG 16384            // per-wave staging: 2 buffers x 8KB
#define OFF_RM  65536            // [32][72] bf16 = 4608 B
#define SMEM_BYTES 70144

typedef short bf16vec8 __attribute__((ext_vector_type(8)));
typedef float f32x4v  __attribute__((ext_vector_type(4)));

__device__ __forceinline__ unsigned int f2bf_u(float f) {
  unsigned int u = __builtin_bit_cast(unsigned int, f);
  return (u + 0x7fffu + ((u >> 16) & 1u)) >> 16;   // RNE
}
__device__ __forceinline__ unsigned int pack2bf(float a, float b) {
  return f2bf_u(a) | (f2bf_u(b) << 16);
}
__device__ __forceinline__ void async_ld16(const void* g, void* l) {
  __builtin_amdgcn_global_load_lds(
      (const __attribute__((address_space(1))) void*)g,
      (__attribute__((address_space(3))) void*)l, 16, 0, 0);
}

__global__ __launch_bounds__(256)
void lrri_prep(const float* __restrict__ W, unsigned short* __restrict__ Wt,
               unsigned short* __restrict__ Wb) {
  const int idx = blockIdx.x * blockDim.x + threadIdx.x;   // 0..65535
  const int k = idx >> 4;
  const int j = (idx & 15) * 4;
  float4 w = *(const float4*)(W + (size_t)k * R_DIM + j);
  ushort4 p;
  p.x = (unsigned short)f2bf_u(w.x);
  p.y = (unsigned short)f2bf_u(w.y);
  p.z = (unsigned short)f2bf_u(w.z);
  p.w = (unsigned short)f2bf_u(w.w);
  *(ushort4*)(Wb + (size_t)k * R_DIM + j) = p;     // [4096][64] bf16
  Wt[(size_t)(j + 0) * D_DIM + k] = p.x;           // [64][4096] bf16
  Wt[(size_t)(j + 1) * D_DIM + k] = p.y;
  Wt[(size_t)(j + 2) * D_DIM + k] = p.z;
  Wt[(size_t)(j + 3) * D_DIM + k] = p.w;
}

template<bool USE_WS>
__global__ __launch_bounds__(256, 2)
void lrri_fused(const float* __restrict__ base, const float* __restrict__ srcp,
                const float* __restrict__ W, const int* __restrict__ subs,
                const unsigned short* __restrict__ Wt_bf,   // [64][4096]
                const unsigned short* __restrict__ Wb_bf,   // [4096][64]
                float* __restrict__ out)
{
  __shared__ __align__(16) unsigned char smem[SMEM_BYTES];
  const int tid  = threadIdx.x;
  const int wave = tid >> 6;
  const int lane = tid & 63;
  const int l4   = lane & 15;
  const int g    = lane >> 4;
  const int rh   = wave >> 1;            // row-half: 16 rows
  const int kh   = wave & 1;             // K-half: 2048 cols
  const long rowbase = (long)blockIdx.x * BM;
  const long rowg    = rowbase + rh * 16;
  unsigned char* wbuf = smem + wave * WAVESTG;

  // ---------------- Phase 1: r = (src-base) @ W over this wave's K half ---
  f32x4v acc[4];
  #pragma unroll
  for (int t = 0; t < 4; ++t) acc[t] = (f32x4v){0.f, 0.f, 0.f, 0.f};

  // stage one 64-float K-chunk of base+src for 16 rows into buffer p (8KB)
  auto stage = [&](int p, int c) {
    const int kb = kh * 2048 + c * 64;                 // floats
    unsigned char* buf = wbuf + p * 8192;
    #pragma unroll
    for (int i = 0; i < 4; ++i) {
      const int  r  = i * 4 + g;                       // row_local 0..15
      const unsigned cb = ((unsigned)(l4 * 16)) ^ ((unsigned)(r & 7) << 4);
      const long goff = (rowg + r) * (long)D_DIM + kb + (cb >> 2);
      async_ld16(base + goff, buf + i * 1024);         // dest: uniform + lane*16
      async_ld16(srcp + goff, buf + 4096 + i * 1024);
    }
  };

  auto compute = [&](int p, int c) {
    const int kb = kh * 2048 + c * 64;
    const unsigned char* buf = wbuf + p * 8192;
    uint4 af[2];
    #pragma unroll
    for (int s = 0; s < 2; ++s) {
      const unsigned x = (unsigned)(l4 & 7) << 4;
      const unsigned cb0 = ((unsigned)(s * 128 + g * 32 +  0)) ^ x;
      const unsigned cb1 = ((unsigned)(s * 128 + g * 32 + 16)) ^ x;
      float4 fb0 = *(const float4*)(buf + l4 * 256 + cb0);
      float4 fb1 = *(const float4*)(buf + l4 * 256 + cb1);
      float4 fs0 = *(const float4*)(buf + 4096 + l4 * 256 + cb0);
      float4 fs1 = *(const float4*)(buf + 4096 + l4 * 256 + cb1);
      af[s].x = pack2bf(fs0.x - fb0.x, fs0.y - fb0.y);
      af[s].y = pack2bf(fs0.z - fb0.z, fs0.w - fb0.w);
      af[s].z = pack2bf(fs1.x - fb1.x, fs1.y - fb1.y);
      af[s].w = pack2bf(fs1.z - fb1.z, fs1.w - fb1.w);
    }
    #pragma unroll
    for (int t = 0; t < 4; ++t) {
      #pragma unroll
      for (int s = 0; s < 2; ++s) {
        uint4 bfrag;
        if (USE_WS) {
          bfrag = *(const uint4*)(Wt_bf + (size_t)(t * 16 + l4) * D_DIM +
                                  kb + s * 32 + g * 8);
        } else {
          unsigned int pq[4];
          #pragma unroll
          for (int e2 = 0; e2 < 4; ++e2) {
            float wa = W[(size_t)(kb + s * 32 + g * 8 + e2 * 2    ) * R_DIM + t * 16 + l4];
            float wb = W[(size_t)(kb + s * 32 + g * 8 + e2 * 2 + 1) * R_DIM + t * 16 + l4];
            pq[e2] = pack2bf(wa, wb);
          }
          bfrag.x = pq[0]; bfrag.y = pq[1]; bfrag.z = pq[2]; bfrag.w = pq[3];
        }
        acc[t] = __builtin_amdgcn_mfma_f32_16x16x32_bf16(
            __builtin_bit_cast(bf16vec8, af[s]),
            __builtin_bit_cast(bf16vec8, bfrag), acc[t], 0, 0, 0);
      }
    }
  };

  stage(0, 0);
  #pragma unroll 1
  for (int c = 0; c < 31; ++c) {
    stage((c + 1) & 1, c + 1);     // prefetch next chunk (async, no VGPRs)
    compute(c & 1, c);
  }
  compute(1, 31);

  // per-wave partials -> own staging buf0 (dead now): [16][72] f32
  {
    float* part = (float*)wbuf;
    #pragma unroll
    for (int t = 0; t < 4; ++t)
      #pragma unroll
      for (int i = 0; i < 4; ++i)
        part[(g * 4 + i) * 72 + t * 16 + l4] = acc[t][i];
  }
  __syncthreads();

  // ---------------- Reduce K-halves + per-row partition mask --------------
  {
    const int row = tid >> 3, jg = tid & 7;     // 32 rows x 8 j-groups
    const int lr  = row & 15;
    const float* pa = (const float*)(smem + ((row >> 4) * 2 + 0) * WAVESTG);
    const float* pb = (const float*)(smem + ((row >> 4) * 2 + 1) * WAVESTG);
    int4 sb = *(const int4*)(subs + (rowbase + row) * 4);
    unsigned mbits = (1u << sb.x) | (1u << sb.y) | (1u << sb.z) | (1u << sb.w);
    unsigned short v[8];
    #pragma unroll
    for (int jj = 0; jj < 8; ++jj) {
      const int j = jg * 8 + jj;
      float sum = pa[lr * 72 + j] + pb[lr * 72 + j];
      v[jj] = ((mbits >> (j >> 3)) & 1u) ? (unsigned short)f2bf_u(sum)
                                         : (unsigned short)0;
    }
    uint4 pk;
    pk.x = (unsigned)v[0] | ((unsigned)v[1] << 16);
    pk.y = (unsigned)v[2] | ((unsigned)v[3] << 16);
    pk.z = (unsigned)v[4] | ((unsigned)v[5] << 16);
    pk.w = (unsigned)v[6] | ((unsigned)v[7] << 16);
    *(uint4*)(smem + OFF_RM + row * 144 + jg * 16) = pk;   // stride 72 shorts
  }
  __syncthreads();

  // ---------------- Phase 2: out = base(global) + rm @ W^T ----------------
  uint4 a2[2][2];     // [row-tile m][k-split s], loaded once (rm is 32x64)
  #pragma unroll
  for (int m = 0; m < 2; ++m)
    #pragma unroll
    for (int s = 0; s < 2; ++s)
      a2[m][s] = *(const uint4*)(smem + OFF_RM + (m * 16 + l4) * 144 +
                                 s * 64 + g * 16);
  float* cbuf = (float*)wbuf;     // [32][72] f32 = 9216 B, wave-private
  #pragma unroll 1
  for (int grp = 0; grp < 16; ++grp) {
    const int cbase = wave * 1024 + grp * 64;
    // base re-read (L2/L3-hot), issued early, independent of MFMAs
    float4 bb[8];
    #pragma unroll
    for (int v2 = 0; v2 < 8; ++v2) {
      const int r = g + v2 * 4;
      bb[v2] = *(const float4*)(base + (rowbase + r) * D_DIM + cbase + l4 * 4);
    }
    f32x4v a[2][4];
    #pragma unroll
    for (int m = 0; m < 2; ++m)
      #pragma unroll
      for (int t = 0; t < 4; ++t) a[m][t] = (f32x4v){0.f, 0.f, 0.f, 0.f};
    #pragma unroll
    for (int t = 0; t < 4; ++t) {
      #pragma unroll
      for (int s = 0; s < 2; ++s) {
        uint4 bfrag;  // B[kk=j][n=col] = W[col][j]; per-lane 8 consecutive j
        if (USE_WS) {
          bfrag = *(const uint4*)(Wb_bf + (size_t)(cbase + t * 16 + l4) * R_DIM +
                                  s * 32 + g * 8);
        } else {
          const float* wp = W + (size_t)(cbase + t * 16 + l4) * R_DIM + s * 32 + g * 8;
          float4 wa = *(const float4*)(wp);
          float4 wb2 = *(const float4*)(wp + 4);
          bfrag.x = pack2bf(wa.x, wa.y); bfrag.y = pack2bf(wa.z, wa.w);
          bfrag.z = pack2bf(wb2.x, wb2.y); bfrag.w = pack2bf(wb2.z, wb2.w);
        }
        #pragma unroll
        for (int m = 0; m < 2; ++m)
          a[m][t] = __builtin_amdgcn_mfma_f32_16x16x32_bf16(
              __builtin_bit_cast(bf16vec8, a2[m][s]),
              __builtin_bit_cast(bf16vec8, bfrag), a[m][t], 0, 0, 0);
      }
    }
    #pragma unroll
    for (int m = 0; m < 2; ++m)
      #pragma unroll
      for (int t = 0; t < 4; ++t)
        #pragma unroll
        for (int i = 0; i < 4; ++i)
          cbuf[(m * 16 + g * 4 + i) * 72 + t * 16 + l4] = a[m][t][i];
    // transpose via wave-local LDS -> coalesced float4 stores
    #pragma unroll
    for (int v2 = 0; v2 < 8; ++v2) {
      const int r = g + v2 * 4;
      f32x4v cv = *(const f32x4v*)(cbuf + r * 72 + l4 * 4);
      float4 o;
      o.x = cv[0] + bb[v2].x;
      o.y = cv[1] + bb[v2].y;
      o.z = cv[2] + bb[v2].z;
      o.w = cv[3] + bb[v2].w;
      *(float4*)(out + (rowbase + r) * D_DIM + cbase + l4 * 4) = o;
    }
  }
}

extern "C" void kernel_launch(void* const* d_in, const int* in_sizes, int n_in,
                              void* d_out, int out_size, void* d_ws, size_t ws_size,
                              hipStream_t stream) {
  const float* base = (const float*)d_in[0];
  const float* srcp = (const float*)d_in[1];
  const float* W    = (const float*)d_in[2];
  const int*   subs = (const int*)d_in[3];
  float* out = (float*)d_out;

  const int nblocks = 16384 / BM;   // 512
  const size_t wbytes = (size_t)2 * R_DIM * D_DIM * sizeof(unsigned short); // 1 MB
  if (d_ws && ws_size >= wbytes) {
    unsigned short* Wt = (unsigned short*)d_ws;          // [64][4096] bf16
    unsigned short* Wb = Wt + (size_t)R_DIM * D_DIM;     // [4096][64] bf16
    lrri_prep<<<256, 256, 0, stream>>>(W, Wt, Wb);
    lrri_fused<true><<<nblocks, 256, 0, stream>>>(base, srcp, W, subs, Wt, Wb, out);
  } else {
    lrri_fused<false><<<nblocks, 256, 0, stream>>>(base, srcp, W, subs, nullptr, nullptr, out);
  }
}